// Round 1
// baseline (668.589 us; speedup 1.0000x reference)
//
#include <hip/hip_runtime.h>

// PackedViterbi via chunked log-semiring scan.
//   V_new[i] = lse_j(theta[t,b,i,j] + V[j]),  T=512, B=64, S=64.
//
// Phase 1: one wave per (b, 16-step chunk): P = A_t15 o ... o A_t0 in linear
//   space (bf16, globally scaled by exp(-8) per step, NO per-step renorm —
//   16-step chunks keep the product inside bf16 range by construction).
//   A-fragments are built in registers directly from global (no LDS round
//   trip); the running product lives in LDS in a conflict-free subtile
//   layout. Single-wave blocks -> NO __syncthreads anywhere, so the
//   next-step prefetch stays in flight across the MFMA phase (no
//   vmcnt(0)-before-barrier drain).
// Phase 2: one wave per b: V <- n*8 + vmax + log(EP . exp(V - vmax)) over
//   active chunks (chunk-ahead prefetch), then terminal logsumexp.

typedef unsigned short u16;
typedef unsigned int   u32;

constexpr int KC  = 16;              // timesteps per chunk
constexpr int NCH = 32;              // chunks per sequence (512/16)
constexpr float A_SHIFT = 8.0f;      // exp(theta - 8): theta ~ N(0,1)
constexpr float LOG2E   = 1.44269504088896340736f;

typedef short bf16x8 __attribute__((ext_vector_type(8)));
typedef float f32x4  __attribute__((ext_vector_type(4)));

__device__ inline u32 bfr(float x) {          // f32 bits + bf16 round increment
    union { float f; u32 u; } v; v.f = x;
    return v.u + 0x8000u;
}
__device__ inline u32 pk2(u32 lo, u32 hi) {   // (hi16(hi)<<16) | hi16(lo)
    return __builtin_amdgcn_perm(hi, lo, 0x07060302u);
}
__device__ inline u32 eb(float t) {           // rounded bf16 bits of exp(t-8)
    return bfr(exp2f(__builtin_fmaf(t, LOG2E, -A_SHIFT * LOG2E)));
}
__device__ inline float bf2f(u32 bits) {
    union { float f; u32 u; } v; v.u = bits << 16;
    return v.f;
}

// Bs subtile layout (8 KB total), element (n, k), g = k>>3, e = k&7:
//   byte = ((n>>4)*2 + (g>>2))*1024 + (g&3)*256 + (n&15)*16 + e*2
// B-frag read for (kt,nt), lane (ls,lq): 16B at (nt*2+kt)*1024 + lq*256 + ls*16
//   -> lane-contiguous 1 KB per instruction: bank-conflict-free ds_read_b128.

// ---------------------------------------------------------------- phase 1
__global__ __launch_bounds__(64, 2) void pv_phase1(
    const float* __restrict__ theta,
    const int*   __restrict__ lengths,
    u16*         __restrict__ ept)      // [B*NCH][64*64] EP^T bf16: [n][m]
{
    const int chunk = blockIdx.x;       // 0..2047
    const int b = chunk >> 5;
    const int c = chunk & 31;
    const int L = lengths[b];
    int n = L - c * KC;
    if (n <= 0) return;
    if (n > KC) n = KC;

    __shared__ u16 Bs[4096];            // 8 KB running product EP^T (subtiled)

    const int lane = threadIdx.x & 63;
    const int ls = lane & 15;
    const int lq = lane >> 4;

    // ---- Bs = identity (bf16): zero own 128 B, then set diagonal element.
    // Single wave: DS ops execute in order, no barrier needed.
    {
        uint4 z; z.x = z.y = z.z = z.w = 0u;
        uint4* zp = (uint4*)((char*)Bs + lane * 128);
        #pragma unroll
        for (int q = 0; q < 8; ++q) zp[q] = z;
        const int blk = (lane >> 4) * 2 + (lane >> 5);        // n=k=lane
        const int idx = blk * 512 + ((lane >> 3) & 3) * 128 + (lane & 15) * 8 + (lane & 7);
        Bs[idx] = 0x3F80;               // 1.0 bf16
    }

    // theta[t][b][i][j]: flat = t*262144 + b*4096 + i*64 + j
    const float* tb = theta + (size_t)(c * KC) * 262144 + (size_t)b * 4096;

    // A-fragment-layout prefetch: q = mt*4 + kt*2 + h covers
    //   row = mt*16+ls, cols kt*32 + lq*8 + h*4 .. +3   (64B-aligned segments)
    float4 pre[16];
    #pragma unroll
    for (int q = 0; q < 16; ++q) {
        const int mt = q >> 2, kt = (q >> 1) & 1, h = q & 1;
        pre[q] = *(const float4*)(tb + (mt * 16 + ls) * 64 + kt * 32 + lq * 8 + h * 4);
    }

    f32x4 acc[4][4];

    for (int s = 0; s < n; ++s) {
        // ---- build A fragments in registers: exp(theta - 8) -> bf16
        bf16x8 af[4][2];
        #pragma unroll
        for (int mt = 0; mt < 4; ++mt)
            #pragma unroll
            for (int kt = 0; kt < 2; ++kt) {
                float4 x = pre[mt * 4 + kt * 2];
                float4 y = pre[mt * 4 + kt * 2 + 1];
                union { u32 w[4]; bf16x8 v; } u;
                u.w[0] = pk2(eb(x.x), eb(x.y));
                u.w[1] = pk2(eb(x.z), eb(x.w));
                u.w[2] = pk2(eb(y.x), eb(y.y));
                u.w[3] = pk2(eb(y.z), eb(y.w));
                af[mt][kt] = u.v;
            }

        // ---- prefetch next timestep; no barrier below, so these stay in
        // flight across the whole MFMA/writeback phase.
        if (s + 1 < n) {
            const float* tn = tb + (size_t)(s + 1) * 262144;
            #pragma unroll
            for (int q = 0; q < 16; ++q) {
                const int mt = q >> 2, kt = (q >> 1) & 1, h = q & 1;
                pre[q] = *(const float4*)(tn + (mt * 16 + ls) * 64 + kt * 32 + lq * 8 + h * 4);
            }
        }

        // ---- B fragments: lane-contiguous, conflict-free
        bf16x8 bf[2][4];
        #pragma unroll
        for (int kt = 0; kt < 2; ++kt)
            #pragma unroll
            for (int nt = 0; nt < 4; ++nt)
                bf[kt][nt] = *(const bf16x8*)((const char*)Bs +
                                ((nt * 2 + kt) * 1024 + lq * 256 + ls * 16));

        #pragma unroll
        for (int mt = 0; mt < 4; ++mt)
            #pragma unroll
            for (int nt = 0; nt < 4; ++nt) {
                f32x4 z4 = {0.f, 0.f, 0.f, 0.f};
                acc[mt][nt] = z4;
            }

        // ---- C = E_A * EP : 32 MFMAs
        #pragma unroll
        for (int mt = 0; mt < 4; ++mt)
            #pragma unroll
            for (int nt = 0; nt < 4; ++nt) {
                acc[mt][nt] = __builtin_amdgcn_mfma_f32_16x16x32_bf16(
                    af[mt][0], bf[0][nt], acc[mt][nt], 0, 0, 0);
                acc[mt][nt] = __builtin_amdgcn_mfma_f32_16x16x32_bf16(
                    af[mt][1], bf[1][nt], acc[mt][nt], 0, 0, 0);
            }

        // C/D layout: col n = nt*16+ls, row m = mt*16 + lq*4 + r.
        // No renorm: 16-step chunk product stays within bf16 range.
        if (s + 1 < n) {
            // write product back to Bs (subtile layout); WAR vs the frag
            // reads above is safe: same-wave DS ops are in order.
            #pragma unroll
            for (int mt = 0; mt < 4; ++mt)
                #pragma unroll
                for (int nt = 0; nt < 4; ++nt) {
                    f32x4 a4 = acc[mt][nt];
                    uint2 w;
                    w.x = pk2(bfr(a4[0]), bfr(a4[1]));
                    w.y = pk2(bfr(a4[2]), bfr(a4[3]));
                    const int byte = (nt * 2 + (mt >> 1)) * 1024
                                   + ((mt * 2 + (lq >> 1)) & 3) * 256
                                   + ls * 16 + (lq & 1) * 8;
                    *(uint2*)((char*)Bs + byte) = w;
                }
        } else {
            // final: store EP^T row-major [n][m] to global
            u16* outp = ept + ((size_t)chunk << 12);
            #pragma unroll
            for (int mt = 0; mt < 4; ++mt)
                #pragma unroll
                for (int nt = 0; nt < 4; ++nt) {
                    f32x4 a4 = acc[mt][nt];
                    uint2 w;
                    w.x = pk2(bfr(a4[0]), bfr(a4[1]));
                    w.y = pk2(bfr(a4[2]), bfr(a4[3]));
                    *(uint2*)&outp[(nt * 16 + ls) * 64 + mt * 16 + lq * 4] = w;
                }
        }
    }
}

// ---------------------------------------------------------------- phase 2
__device__ inline float chunk_step(const u32 (&raw)[64], float V, int nst,
                                   float* evs, int lane) {
    float vmax = V;
    #pragma unroll
    for (int off = 1; off < 64; off <<= 1)
        vmax = fmaxf(vmax, __shfl_xor(vmax, off, 64));
    evs[lane] = __expf(V - vmax);      // same-wave LDS: in-order, no barrier

    float ev[64];
    #pragma unroll
    for (int q = 0; q < 16; ++q) {
        float4 e4 = *(const float4*)&evs[q * 4];     // broadcast reads
        ev[q * 4 + 0] = e4.x; ev[q * 4 + 1] = e4.y;
        ev[q * 4 + 2] = e4.z; ev[q * 4 + 3] = e4.w;
    }

    float y0 = 0.f, y1 = 0.f, y2 = 0.f, y3 = 0.f;
    #pragma unroll
    for (int j = 0; j < 64; j += 4) {
        y0 += bf2f(raw[j + 0]) * ev[j + 0];
        y1 += bf2f(raw[j + 1]) * ev[j + 1];
        y2 += bf2f(raw[j + 2]) * ev[j + 2];
        y3 += bf2f(raw[j + 3]) * ev[j + 3];
    }
    const float y = (y0 + y1) + (y2 + y3);
    return (float)nst * A_SHIFT + vmax + __logf(y);
}

__global__ __launch_bounds__(64, 1) void pv_phase2(
    const u16*   __restrict__ ept,
    const int*   __restrict__ lengths,
    float*       __restrict__ out)
{
    const int b = blockIdx.x;
    const int lane = threadIdx.x & 63;
    const int L = lengths[b];
    const int nc = (L + KC - 1) / KC;

    __shared__ float evs[64];
    float V = 0.0f;

    const u16* Mbase = ept + ((size_t)b * NCH << 12);
    u32 rawA[64], rawB[64];

    // lane i consumes EP row i = EP^T column i
    #pragma unroll
    for (int j = 0; j < 64; ++j)
        rawA[j] = (u32)Mbase[j * 64 + lane];

    int c = 0;
    while (true) {
        int nst = L - c * KC; if (nst > KC) nst = KC;
        if (c + 1 < nc) {                               // prefetch next chunk
            const u16* M = Mbase + ((size_t)(c + 1) << 12);
            #pragma unroll
            for (int j = 0; j < 64; ++j) rawB[j] = (u32)M[j * 64 + lane];
        }
        V = chunk_step(rawA, V, nst, evs, lane);
        if (++c >= nc) break;

        nst = L - c * KC; if (nst > KC) nst = KC;
        if (c + 1 < nc) {
            const u16* M = Mbase + ((size_t)(c + 1) << 12);
            #pragma unroll
            for (int j = 0; j < 64; ++j) rawA[j] = (u32)M[j * 64 + lane];
        }
        V = chunk_step(rawB, V, nst, evs, lane);
        if (++c >= nc) break;
    }

    // terminal logsumexp over states
    float vmax = V;
    #pragma unroll
    for (int off = 1; off < 64; off <<= 1)
        vmax = fmaxf(vmax, __shfl_xor(vmax, off, 64));
    float ssum = __expf(V - vmax);
    #pragma unroll
    for (int off = 1; off < 64; off <<= 1)
        ssum += __shfl_xor(ssum, off, 64);
    if (lane == 0) out[b] = vmax + __logf(ssum);
}

// ---------------------------------------------------------------- launch
extern "C" void kernel_launch(void* const* d_in, const int* in_sizes, int n_in,
                              void* d_out, int out_size, void* d_ws, size_t ws_size,
                              hipStream_t stream) {
    const float* theta   = (const float*)d_in[0];   // [512,64,64,64] fp32
    const int*   lengths = (const int*)d_in[1];     // [64] int32
    float*       out     = (float*)d_out;           // [64] fp32

    // workspace: EP^T bf16 [2048][4096] (16.78 MB)
    u16* ept = (u16*)d_ws;

    pv_phase1<<<64 * NCH, 64, 0, stream>>>(theta, lengths, ept);
    pv_phase2<<<64, 64, 0, stream>>>(ept, lengths, out);
}